// Round 10
// baseline (259.312 us; speedup 1.0000x reference)
//
#include <hip/hip_runtime.h>
#include <hip/hip_bf16.h>
#include <math.h>

#define IN_CHN 128
#define OUT_CHN 128
#define KD 192
#define TM 64                  // edges per tile

typedef __bf16 bf16x8 __attribute__((ext_vector_type(8)));
typedef float f32x4 __attribute__((ext_vector_type(4)));

static __device__ __forceinline__ unsigned short f2b(float f) {
    return __builtin_bit_cast(unsigned short, (__bf16)f);   // RNE
}
static __device__ __forceinline__ float b2f(unsigned short b) {
    return __uint_as_float(((unsigned int)b) << 16);
}
static __device__ __forceinline__ float fast_tanh(float x) {
    float e = __expf(2.0f * x);
    return 1.0f - 2.0f * __builtin_amdgcn_rcpf(e + 1.0f);
}

// async global->LDS, 16B per lane; LDS dest wave-uniform base + lane*16
#define GLL16(gsrc, ldst) \
    __builtin_amdgcn_global_load_lds( \
        (const __attribute__((address_space(1))) unsigned int*)(gsrc), \
        (__attribute__((address_space(3))) unsigned int*)(ldst), 16, 0, 0)

// light barrier: cross-wave LDS visibility WITHOUT draining vmcnt (keeps
// in-flight global_load_lds alive across it)
#define LDS_BARRIER() do { \
    asm volatile("s_waitcnt lgkmcnt(0)" ::: "memory"); \
    __builtin_amdgcn_s_barrier(); \
    __builtin_amdgcn_sched_barrier(0); \
} while (0)

// ---------------- x -> bf16 pre-conversion ----------------

__global__ __launch_bounds__(256) void cvt_x(const float* __restrict__ x,
    unsigned short* __restrict__ xb, long long n8)
{
    long long i = (long long)blockIdx.x * 256 + threadIdx.x;
    if (i >= n8) return;
    const float4* src = (const float4*)(x + i * 8);
    float4 v0 = src[0], v1 = src[1];
    ushort4 p0 = { f2b(v0.x), f2b(v0.y), f2b(v0.z), f2b(v0.w) };
    ushort4 p1 = { f2b(v1.x), f2b(v1.y), f2b(v1.z), f2b(v1.w) };
    *(ushort4*)(xb + i * 8)     = p0;
    *(ushort4*)(xb + i * 8 + 4) = p1;
}

// ---------------- CSR build ----------------

__global__ __launch_bounds__(256) void count_deg(const int* __restrict__ ei,
                                                 int* __restrict__ deg, int E) {
    int e = blockIdx.x * 256 + threadIdx.x;
    if (e < E) atomicAdd(&deg[ei[E + e]], 1);
}

static __device__ __forceinline__ int wave_incl_scan(int v, int lane) {
    #pragma unroll
    for (int off = 1; off < 64; off <<= 1) {
        int t = __shfl_up(v, off);
        if (lane >= off) v += t;
    }
    return v;
}

__global__ __launch_bounds__(256) void scan_local(const int* __restrict__ deg,
    int* __restrict__ offs, int* __restrict__ partial, int Nn)
{
    __shared__ int wsum[4];
    int tid = threadIdx.x, lane = tid & 63, wid = tid >> 6;
    int i = blockIdx.x * 256 + tid;
    int v = (i < Nn) ? deg[i] : 0;
    int incl = wave_incl_scan(v, lane);
    if (lane == 63) wsum[wid] = incl;
    __syncthreads();
    int wpre = 0;
    for (int w = 0; w < wid; ++w) wpre += wsum[w];
    if (i < Nn) offs[i] = wpre + incl - v;
    if (tid == 255) partial[blockIdx.x] = wpre + incl;
}

__global__ __launch_bounds__(256) void scan_partial(int* __restrict__ partial, int nparts)
{
    __shared__ int wsum[4];
    int tid = threadIdx.x, lane = tid & 63, wid = tid >> 6;
    int v = (tid < nparts) ? partial[tid] : 0;
    int incl = wave_incl_scan(v, lane);
    if (lane == 63) wsum[wid] = incl;
    __syncthreads();
    int wpre = 0;
    for (int w = 0; w < wid; ++w) wpre += wsum[w];
    if (tid < nparts) partial[tid] = wpre + incl - v;
}

__global__ __launch_bounds__(256) void finalize_offs(int* __restrict__ offs,
    const int* __restrict__ partial, int* __restrict__ cursor, int Nn, int E)
{
    int i = blockIdx.x * 256 + threadIdx.x;
    if (i < Nn) {
        int o = offs[i] + partial[i >> 8];
        offs[i] = o; cursor[i] = o;
        if (i == Nn - 1) offs[Nn] = E;   // sentinel
    }
}

// scatter (src, t) into CSR-permuted order + node id per slot
__global__ __launch_bounds__(256) void fill_perm(const int* __restrict__ ei,
    const float* __restrict__ et, int* __restrict__ cursor,
    uint2* __restrict__ mt, int* __restrict__ nid, int E)
{
    int e = blockIdx.x * 256 + threadIdx.x;
    if (e < E) {
        int d = ei[E + e];
        int pos = atomicAdd(&cursor[d], 1);
        mt[pos] = make_uint2((unsigned)ei[e], __float_as_uint(et[e]));
        nid[pos] = d;
    }
}

// ---------------- fused MFMA GEMM + softmax aggregation ----------------
// Per edge (CSR order): h = tanh([x[src], te(t)] @ W^T + b), ex = exp(h.attn).
// out_raw[dst] += ex*h and den[dst] += ex accumulate IN-KERNEL: h tile stays
// in LDS (hx), alpha reduced cross-wave via LDS float atomics (exs).
// Blocks own CONTIGUOUS tile ranges; wave w aggregates nodes n%8==w with
// register carry across tiles. Node fully inside block -> plain store;
// block-boundary nodes -> global atomicAdd (~2/block). normalize() divides.
// Schedule/tile machinery (xs gll dbuf + src-side swizzle, te stage, W regs)
// carried verbatim from R9. LDS = 32K xs + 8K te + 17K hx + exs = 58624 B.

__device__ __forceinline__ void load_meta(const uint2* __restrict__ mt,
    int tile, int E, int rbase, int g, int trow, int sv[2], float& tsv)
{
    int e0 = tile * TM;
    #pragma unroll
    for (int i = 0; i < 2; ++i) {
        int e = e0 + rbase + i * 4 + g;
        sv[i] = (int)mt[e < E ? e : E - 1].x;
    }
    int el = e0 + trow;
    tsv = __uint_as_float(mt[el < E ? el : E - 1].y);
}

__global__ __launch_bounds__(512) void gemm_fused(
    const unsigned short* __restrict__ xb, const uint2* __restrict__ mt,
    const int* __restrict__ nid, const int* __restrict__ offs,
    const float* __restrict__ freqs, const float* __restrict__ lw,
    const float* __restrict__ lb, const float* __restrict__ attn,
    float* __restrict__ out, float* __restrict__ den_g,
    int E, int Nn, int n_tiles, int kq, int kr)
{
    __shared__ unsigned short xs[2][TM][128];   // 32 KB x tile (dbuf)
    __shared__ unsigned short te[TM * 64];      //  8 KB te tile (swizzled)
    __shared__ unsigned short hx[TM][136];      // 17 KB h tile (pad: 272B rows)
    __shared__ float exs[TM];                   // alpha accumulators

    const int b    = blockIdx.x;
    const int t0   = b * kq + min(b, kr);
    const int cnt  = kq + (b < kr ? 1 : 0);
    if (cnt <= 0 || t0 >= n_tiles) return;
    const int tend = min(t0 + cnt, n_tiles);
    const int be0  = t0 * TM;                   // block's first edge
    const int bend = min(tend * TM, E);         // block's edge end

    const int tid  = threadIdx.x;
    const int lane = tid & 63;
    const int wv   = tid >> 6;          // wave 0..7
    const int c16  = lane & 15;
    const int g    = lane >> 4;         // 0..3
    const int wbase = wv * 16;          // this wave's channel base
    const int rbase = wv * 8;           // this wave's gll row base
    const int trow  = tid >> 3;         // te row 0..63
    const int tpart = tid & 7;          // te part 0..7 (0-3 sin, 4-7 cos)
    const int sub  = lane >> 4;         // agg: edge subgroup 0..3
    const int chl  = lane & 15;         // agg: channel lane (8 ch)

    // W frags in registers: lane's row(ch) = wbase+c16; k = kk*32+g*8+j
    bf16x8 Wf[6];
    #pragma unroll
    for (int kk = 0; kk < 6; ++kk) {
        const float* wp = lw + (size_t)(wbase + c16) * KD + kk * 32 + g * 8;
        float4 v0 = *(const float4*)wp;
        float4 v1 = *(const float4*)(wp + 4);
        bf16x8 bb;
        bb[0] = (__bf16)v0.x; bb[1] = (__bf16)v0.y; bb[2] = (__bf16)v0.z; bb[3] = (__bf16)v0.w;
        bb[4] = (__bf16)v1.x; bb[5] = (__bf16)v1.y; bb[6] = (__bf16)v1.z; bb[7] = (__bf16)v1.w;
        Wf[kk] = bb;
    }
    const f32x4 bias_v = *(const f32x4*)(lb   + wbase + g * 4);
    const f32x4 attn_v = *(const f32x4*)(attn + wbase + g * 4);

    const float coff = (tpart >= 4) ? 1.5707963267948966f : 0.0f;  // cos = sin(x+pi/2)
    float frv[8];
    #pragma unroll
    for (int j = 0; j < 8; ++j) frv[j] = freqs[(tpart & 3) * 8 + j] * 6.283185307179586f;

    // ---- aggregation state (per wave; wave w owns nodes n%8==w) ----
    int n0 = nid[be0];
    int cur_node = n0 + ((wv - (n0 & 7)) & 7);
    float a[8];
    #pragma unroll
    for (int q = 0; q < 8; ++q) a[q] = 0.0f;
    float den = 0.0f;

    float ts_cur, ts_nxt;
    int sv_nxt[2];
    {
        int sv0[2];
        load_meta(mt, t0, E, rbase, g, trow, sv0, ts_cur);
        #pragma unroll
        for (int i = 0; i < 2; ++i) {
            const int rlo = (rbase + i * 4 + g) & 15;
            const unsigned short* gsrc = xb + (size_t)sv0[i] * IN_CHN + ((c16 ^ rlo) * 8);
            GLL16(gsrc, &xs[0][rbase + i * 4][0]);
        }
        int t1 = t0 + 1;
        load_meta(mt, t1 < tend ? t1 : tend - 1, E, rbase, g, trow, sv_nxt, ts_nxt);
    }

    int cur = 0;
    for (int tile = t0; tile < tend; ++tile) {
        const int e0 = tile * TM;
        const int e1 = e0 + TM;

        // ---- compute te(t) pack in registers (overlaps gll(t) drain) ----
        ushort4 tp[2];
        {
            float v[8];
            #pragma unroll
            for (int j = 0; j < 8; ++j)
                v[j] = __sinf(ts_cur * frv[j] + coff);
            tp[0] = (ushort4){ f2b(v[0]), f2b(v[1]), f2b(v[2]), f2b(v[3]) };
            tp[1] = (ushort4){ f2b(v[4]), f2b(v[5]), f2b(v[6]), f2b(v[7]) };
        }
        // ---- prefetch meta(t+2) ----
        int sv2[2]; float ts2;
        {
            int t2 = tile + 2;
            load_meta(mt, t2 < tend ? t2 : tend - 1, E, rbase, g, trow, sv2, ts2);
        }

        __syncthreads();   // A: drains gll(t); agg(t-1) readers of hx/exs done

        // ---- issue gll(t+1) -> xs[cur^1] ----
        if (tile + 1 < tend) {
            #pragma unroll
            for (int i = 0; i < 2; ++i) {
                const int rlo = (rbase + i * 4 + g) & 15;
                const unsigned short* gsrc = xb + (size_t)sv_nxt[i] * IN_CHN + ((c16 ^ rlo) * 8);
                GLL16(gsrc, &xs[cur ^ 1][rbase + i * 4][0]);
            }
        }
        // ---- write te(t) (granule-swizzled) + zero exs ----
        {
            unsigned short* tr = &te[trow * 64];
            int slot = (tpart ^ (trow & 7)) * 8;
            *(ushort4*)(tr + slot)     = tp[0];
            *(ushort4*)(tr + slot + 4) = tp[1];
            if (tid < TM) exs[tid] = 0.0f;
        }

        LDS_BARRIER();     // B: te + exs-zero visible; gll(t+1) in flight

        // ---- MFMA ----
        f32x4 acc[4];
        #pragma unroll
        for (int mi = 0; mi < 4; ++mi) acc[mi] = (f32x4){0.f, 0.f, 0.f, 0.f};

        __builtin_amdgcn_s_setprio(1);
        const unsigned short* xsc = &xs[cur][0][0];
        #pragma unroll
        for (int mi = 0; mi < 4; ++mi) {
            const int r = mi * 16 + c16;
            const unsigned short* xrow = xsc + r * 128;
            #pragma unroll
            for (int kk = 0; kk < 4; ++kk) {
                const int slot = ((kk << 2) + g) ^ c16;   // source-swizzled granule
                bf16x8 av = __builtin_bit_cast(bf16x8, *(const uint4*)(xrow + slot * 8));
                acc[mi] = __builtin_amdgcn_mfma_f32_16x16x32_bf16(Wf[kk], av, acc[mi], 0, 0, 0);
            }
            const unsigned short* trw = &te[r * 64];
            bf16x8 s8 = __builtin_bit_cast(bf16x8, *(const uint4*)(trw + ((g ^ (r & 7)) * 8)));
            bf16x8 c8 = __builtin_bit_cast(bf16x8, *(const uint4*)(trw + (((g + 4) ^ (r & 7)) * 8)));
            acc[mi] = __builtin_amdgcn_mfma_f32_16x16x32_bf16(Wf[4], s8, acc[mi], 0, 0, 0);
            acc[mi] = __builtin_amdgcn_mfma_f32_16x16x32_bf16(Wf[5], c8, acc[mi], 0, 0, 0);
        }
        __builtin_amdgcn_s_setprio(0);

        // ---- epilogue: tanh, h -> hx LDS, alpha -> exs (LDS atomic) ----
        #pragma unroll
        for (int mi = 0; mi < 4; ++mi) {
            const int r = mi * 16 + c16;
            f32x4 z = acc[mi];
            float p = 0.0f;
            #pragma unroll
            for (int q = 0; q < 4; ++q) {
                float h = fast_tanh(z[q] + bias_v[q]);
                z[q] = h;
                p = fmaf(h, attn_v[q], p);
            }
            ushort4 pv = (ushort4){ f2b(z[0]), f2b(z[1]), f2b(z[2]), f2b(z[3]) };
            *(ushort4*)&hx[r][wbase + g * 4] = pv;
            p += __shfl_xor(p, 16);
            p += __shfl_xor(p, 32);
            if (g == 0) atomicAdd(&exs[r], p);
        }

        LDS_BARRIER();     // C: hx + exs complete; gll(t+1) still in flight

        // ---- aggregation: wave w walks its nodes in [e0, e1) ----
        while (cur_node < Nn) {
            int s  = offs[cur_node];
            if (s >= e1) break;
            int en = offs[cur_node + 1];
            int lo = s > e0 ? s : e0;
            int hi = en < e1 ? en : e1;
            for (int i = lo + sub; i < hi; i += 4) {
                int li = i - e0;
                float ex = __expf(exs[li]);
                uint4 hv = *(const uint4*)&hx[li][chl * 8];
                den += ex;
                unsigned int hw[4] = { hv.x, hv.y, hv.z, hv.w };
                #pragma unroll
                for (int q = 0; q < 4; ++q) {
                    a[2*q]   = fmaf(ex, b2f((unsigned short)(hw[q] & 0xFFFFu)), a[2*q]);
                    a[2*q+1] = fmaf(ex, b2f((unsigned short)(hw[q] >> 16)),     a[2*q+1]);
                }
            }
            if (en <= e1) {
                // node complete: reduce across subs and flush
                #pragma unroll
                for (int q = 0; q < 8; ++q) {
                    a[q] += __shfl_xor(a[q], 16);
                    a[q] += __shfl_xor(a[q], 32);
                }
                float ds = den + __shfl_xor(den, 16);
                ds += __shfl_xor(ds, 32);
                float* op = out + (size_t)cur_node * OUT_CHN + chl * 8;
                if (s >= be0) {            // interior: sole writer
                    if (sub == 0) {
                        *(float4*)op       = (float4){a[0], a[1], a[2], a[3]};
                        *(float4*)(op + 4) = (float4){a[4], a[5], a[6], a[7]};
                        if (chl == 0) den_g[cur_node] = ds;
                    }
                } else {                   // straddles block start: atomic
                    if (sub == 0) {
                        #pragma unroll
                        for (int q = 0; q < 8; ++q) atomicAdd(op + q, a[q]);
                        if (chl == 0) atomicAdd(&den_g[cur_node], ds);
                    }
                }
                #pragma unroll
                for (int q = 0; q < 8; ++q) a[q] = 0.0f;
                den = 0.0f;
                cur_node += 8;
            } else break;   // carries into next tile
        }

        ts_cur = ts_nxt; ts_nxt = ts2;
        sv_nxt[0] = sv2[0]; sv_nxt[1] = sv2[1];
        cur ^= 1;
    }

    // ---- block-end flush: carried node spans past block range -> atomic ----
    if (cur_node < Nn) {
        int s = offs[cur_node];
        if (s < bend && offs[cur_node + 1] > bend) {
            #pragma unroll
            for (int q = 0; q < 8; ++q) {
                a[q] += __shfl_xor(a[q], 16);
                a[q] += __shfl_xor(a[q], 32);
            }
            float ds = den + __shfl_xor(den, 16);
            ds += __shfl_xor(ds, 32);
            if (sub == 0) {
                float* op = out + (size_t)cur_node * OUT_CHN + chl * 8;
                #pragma unroll
                for (int q = 0; q < 8; ++q) atomicAdd(op + q, a[q]);
                if (chl == 0) atomicAdd(&den_g[cur_node], ds);
            }
        }
    }
}

// ---------------- normalize: out = out_raw / (den + 1e-16) ----------------

__global__ __launch_bounds__(256) void normalize(float* __restrict__ out,
    const float* __restrict__ den_g, int Nn)
{
    int gid = blockIdx.x * 256 + threadIdx.x;   // one float4 per thread
    int n = gid >> 5;
    if (n >= Nn) return;
    int c = (gid & 31) * 4;
    float rs = __builtin_amdgcn_rcpf(den_g[n] + 1e-16f);
    float4* p = (float4*)(out + (size_t)n * OUT_CHN + c);
    float4 v = *p;
    v.x *= rs; v.y *= rs; v.z *= rs; v.w *= rs;
    *p = v;
}

// ---------------- launch ----------------

extern "C" void kernel_launch(void* const* d_in, const int* in_sizes, int n_in,
                              void* d_out, int out_size, void* d_ws, size_t ws_size,
                              hipStream_t stream) {
    const float* x     = (const float*)d_in[0];
    const int*   ei    = (const int*)d_in[1];     // [2, E]
    const float* et    = (const float*)d_in[2];
    const float* freqs = (const float*)d_in[3];
    const float* lw    = (const float*)d_in[4];   // [128, 192]
    const float* lb    = (const float*)d_in[5];
    const float* attn  = (const float*)d_in[6];
    float* out = (float*)d_out;

    const int E  = in_sizes[2];
    const int Nn = in_sizes[0] / IN_CHN;

    // workspace layout
    char* ws = (char*)d_ws;
    uint2* mt      = (uint2*)ws;         size_t off = (size_t)E * sizeof(uint2);
    int*   nid     = (int*)(ws + off);   off += (size_t)E * sizeof(int);
    unsigned short* xb = (unsigned short*)(ws + off); off += (size_t)Nn * IN_CHN * sizeof(unsigned short);
    float* den_g   = (float*)(ws + off); off += (size_t)Nn * sizeof(float);
    int*   deg     = (int*)(ws + off);   off += (size_t)Nn * sizeof(int);
    int*   offs    = (int*)(ws + off);   off += (size_t)(Nn + 1) * sizeof(int);
    int*   cursor  = (int*)(ws + off);   off += (size_t)Nn * sizeof(int);
    int*   partial = (int*)(ws + off);

    const int nblk = (Nn + 255) / 256;
    const int eblk = (E + 255) / 256;

    long long n8 = (long long)Nn * IN_CHN / 8;
    cvt_x<<<(unsigned)((n8 + 255) / 256), 256, 0, stream>>>(x, xb, n8);

    hipMemsetAsync(deg, 0, (size_t)Nn * sizeof(int), stream);
    count_deg<<<eblk, 256, 0, stream>>>(ei, deg, E);
    scan_local<<<nblk, 256, 0, stream>>>(deg, offs, partial, Nn);
    scan_partial<<<1, 256, 0, stream>>>(partial, nblk);
    finalize_offs<<<nblk, 256, 0, stream>>>(offs, partial, cursor, Nn, E);
    fill_perm<<<eblk, 256, 0, stream>>>(ei, et, cursor, mt, nid, E);

    hipMemsetAsync(out, 0, (size_t)out_size * sizeof(float), stream);
    hipMemsetAsync(den_g, 0, (size_t)Nn * sizeof(float), stream);

    const int n_tiles = (E + TM - 1) / TM;
    const int NB = 512;                       // 2 blocks/CU, contiguous chunks
    const int kq = n_tiles / NB, kr = n_tiles % NB;
    gemm_fused<<<NB, 512, 0, stream>>>(xb, mt, nid, offs, freqs, lw, lb, attn,
                                       out, den_g, E, Nn, n_tiles, kq, kr);

    normalize<<<(Nn * 32 + 255) / 256, 256, 0, stream>>>(out, den_g, Nn);
}

// Round 11
// 250.395 us; speedup vs baseline: 1.0356x; 1.0356x over previous
//
#include <hip/hip_runtime.h>
#include <hip/hip_bf16.h>
#include <math.h>

#define IN_CHN 128
#define OUT_CHN 128
#define KD 192
#define TM 64                  // edges per tile
#define HXP 136                // hx row stride in ushorts (272B, 16B-aligned)

typedef __bf16 bf16x8 __attribute__((ext_vector_type(8)));
typedef float f32x4 __attribute__((ext_vector_type(4)));

static __device__ __forceinline__ unsigned short f2b(float f) {
    return __builtin_bit_cast(unsigned short, (__bf16)f);   // RNE
}
static __device__ __forceinline__ float b2f(unsigned short b) {
    return __uint_as_float(((unsigned int)b) << 16);
}
static __device__ __forceinline__ float fast_tanh(float x) {
    float e = __expf(2.0f * x);
    return 1.0f - 2.0f * __builtin_amdgcn_rcpf(e + 1.0f);
}

// async global->LDS, 16B per lane; LDS dest wave-uniform base + lane*16
#define GLL16(gsrc, ldst) \
    __builtin_amdgcn_global_load_lds( \
        (const __attribute__((address_space(1))) unsigned int*)(gsrc), \
        (__attribute__((address_space(3))) unsigned int*)(ldst), 16, 0, 0)

// light barrier: cross-wave LDS visibility WITHOUT draining vmcnt (keeps
// in-flight global_load_lds alive across it)
#define LDS_BARRIER() do { \
    asm volatile("s_waitcnt lgkmcnt(0)" ::: "memory"); \
    __builtin_amdgcn_s_barrier(); \
    __builtin_amdgcn_sched_barrier(0); \
} while (0)

// ---------------- x -> bf16 + init deg/side ----------------

__global__ __launch_bounds__(256) void cvt_init(const float* __restrict__ x,
    unsigned short* __restrict__ xb, int* __restrict__ deg,
    int* __restrict__ side_node, long long n8, int Nn, int nb)
{
    long long i = (long long)blockIdx.x * 256 + threadIdx.x;
    if (i < n8) {
        const float4* src = (const float4*)(x + i * 8);
        float4 v0 = src[0], v1 = src[1];
        ushort4 p0 = { f2b(v0.x), f2b(v0.y), f2b(v0.z), f2b(v0.w) };
        ushort4 p1 = { f2b(v1.x), f2b(v1.y), f2b(v1.z), f2b(v1.w) };
        *(ushort4*)(xb + i * 8)     = p0;
        *(ushort4*)(xb + i * 8 + 4) = p1;
    }
    int t = (int)i;
    if (t < Nn) deg[t] = 0;
    if (t < nb) side_node[t] = -1;
}

// ---------------- CSR build ----------------

__global__ __launch_bounds__(256) void count_deg(const int* __restrict__ ei,
                                                 int* __restrict__ deg, int E) {
    int e = blockIdx.x * 256 + threadIdx.x;
    if (e < E) atomicAdd(&deg[ei[E + e]], 1);
}

static __device__ __forceinline__ int wave_incl_scan(int v, int lane) {
    #pragma unroll
    for (int off = 1; off < 64; off <<= 1) {
        int t = __shfl_up(v, off);
        if (lane >= off) v += t;
    }
    return v;
}

__global__ __launch_bounds__(256) void scan_local(const int* __restrict__ deg,
    int* __restrict__ offs, int* __restrict__ partial, int Nn)
{
    __shared__ int wsum[4];
    int tid = threadIdx.x, lane = tid & 63, wid = tid >> 6;
    int i = blockIdx.x * 256 + tid;
    int v = (i < Nn) ? deg[i] : 0;
    int incl = wave_incl_scan(v, lane);
    if (lane == 63) wsum[wid] = incl;
    __syncthreads();
    int wpre = 0;
    for (int w = 0; w < wid; ++w) wpre += wsum[w];
    if (i < Nn) offs[i] = wpre + incl - v;
    if (tid == 255) partial[blockIdx.x] = wpre + incl;
}

// per-block: sum partials[0..b) directly (nblk <= 256), add, write cursor
__global__ __launch_bounds__(256) void finalize2(int* __restrict__ offs,
    const int* __restrict__ partial, int* __restrict__ cursor,
    int Nn, int E, int nblk)
{
    __shared__ int wsum[4];
    int b = blockIdx.x, tid = threadIdx.x, lane = tid & 63, wid = tid >> 6;
    int v = (tid < b && tid < nblk) ? partial[tid] : 0;
    #pragma unroll
    for (int off = 32; off > 0; off >>= 1) v += __shfl_xor(v, off);
    if (lane == 0) wsum[wid] = v;
    __syncthreads();
    int bp = wsum[0] + wsum[1] + wsum[2] + wsum[3];
    int i = b * 256 + tid;
    if (i < Nn) {
        int o = offs[i] + bp;
        offs[i] = o; cursor[i] = o;
        if (i == Nn - 1) offs[Nn] = E;   // sentinel
    }
}

// scatter (src, t) into CSR-permuted order as one 8B store
__global__ __launch_bounds__(256) void fill_perm(const int* __restrict__ ei,
    const float* __restrict__ et, int* __restrict__ cursor,
    uint2* __restrict__ mt, int E)
{
    int e = blockIdx.x * 256 + threadIdx.x;
    if (e < E) {
        int d = ei[E + e];
        int pos = atomicAdd(&cursor[d], 1);
        mt[pos] = make_uint2((unsigned)ei[e], __float_as_uint(et[e]));
    }
}

// ---------------- fused MFMA GEMM + softmax aggregation ----------------
// Per edge (CSR order): h = tanh([x[src], te(t)] @ W^T + b), ex = exp(h.attn).
// out_raw[dst] += ex*h, den[dst] += ex accumulate in-kernel (hx tile in LDS,
// exs via LDS atomics). Blocks own contiguous tile ranges; wave w aggregates
// nodes n%8==w with register carry. Every completed node -> PLAIN store; the
// block-end straddler -> side[] buffer combined by fixup(). te and hx share
// one LDS union (disjoint lifetimes, split by light barrier C).
// LDS = 32K xs + 17.25K union = 50432 B -> 3 blocks/CU (24 waves).
// Barriers/tile: A(full: drains gll(t), fences agg(t-1)) -> gll(t+1) issue,
// te write, exs zero -> B -> MFMA -> C -> epilogue(hx,exs) -> D -> agg.

__device__ __forceinline__ void load_meta(const uint2* __restrict__ mt,
    int tile, int E, int rbase, int g, int trow, int sv[2], float& tsv)
{
    int e0 = tile * TM;
    #pragma unroll
    for (int i = 0; i < 2; ++i) {
        int e = e0 + rbase + i * 4 + g;
        sv[i] = (int)mt[e < E ? e : E - 1].x;
    }
    int el = e0 + trow;
    tsv = __uint_as_float(mt[el < E ? el : E - 1].y);
}

__global__ __launch_bounds__(512) void gemm_fused(
    const unsigned short* __restrict__ xb, const uint2* __restrict__ mt,
    const int* __restrict__ offs,
    const float* __restrict__ freqs, const float* __restrict__ lw,
    const float* __restrict__ lb, const float* __restrict__ attn,
    float* __restrict__ out, float* __restrict__ den_g,
    int* __restrict__ side_node, float* __restrict__ side_den,
    float* __restrict__ side_val,
    int E, int Nn, int n_tiles, int kq, int kr)
{
    __shared__ unsigned short xs[2][TM][128];          // 32768 B
    __shared__ __align__(16) unsigned short uni[TM * HXP + 128];  // 17664 B union
    unsigned short* te = uni;                          // [64][64], B->MFMA
    unsigned short* hx = uni;                          // [64][HXP], epi->agg
    float* exs = (float*)(uni + TM * HXP);             // 64 floats (above te's 8K)

    const int b    = blockIdx.x;
    const int t0   = b * kq + min(b, kr);
    const int cnt  = kq + (b < kr ? 1 : 0);
    if (cnt <= 0 || t0 >= n_tiles) return;
    const int tend = min(t0 + cnt, n_tiles);
    const int be0  = t0 * TM;
    const int bend = min(tend * TM, E);

    const int tid  = threadIdx.x;
    const int lane = tid & 63;
    const int wv   = tid >> 6;          // wave 0..7
    const int c16  = lane & 15;
    const int g    = lane >> 4;         // 0..3
    const int wbase = wv * 16;          // this wave's channel base
    const int rbase = wv * 8;           // this wave's gll row base
    const int trow  = tid >> 3;         // te row 0..63
    const int tpart = tid & 7;          // te part (0-3 sin, 4-7 cos)
    const int sub  = lane >> 4;         // agg: edge subgroup 0..3
    const int chl  = lane & 15;         // agg: channel lane (8 ch)

    // W frags in registers: lane's row(ch) = wbase+c16; k = kk*32+g*8+j
    bf16x8 Wf[6];
    #pragma unroll
    for (int kk = 0; kk < 6; ++kk) {
        const float* wp = lw + (size_t)(wbase + c16) * KD + kk * 32 + g * 8;
        float4 v0 = *(const float4*)wp;
        float4 v1 = *(const float4*)(wp + 4);
        bf16x8 bb;
        bb[0] = (__bf16)v0.x; bb[1] = (__bf16)v0.y; bb[2] = (__bf16)v0.z; bb[3] = (__bf16)v0.w;
        bb[4] = (__bf16)v1.x; bb[5] = (__bf16)v1.y; bb[6] = (__bf16)v1.z; bb[7] = (__bf16)v1.w;
        Wf[kk] = bb;
    }
    const f32x4 bias_v = *(const f32x4*)(lb   + wbase + g * 4);
    const f32x4 attn_v = *(const f32x4*)(attn + wbase + g * 4);

    const float coff = (tpart >= 4) ? 1.5707963267948966f : 0.0f;
    float frv[8];
    #pragma unroll
    for (int j = 0; j < 8; ++j) frv[j] = freqs[(tpart & 3) * 8 + j] * 6.283185307179586f;

    // ---- first node of block: binary search offs (uniform across threads) ----
    int n0;
    {
        int lo = 0, hi = Nn;
        while (lo + 1 < hi) {
            int mid = (lo + hi) >> 1;
            if (offs[mid] <= be0) lo = mid; else hi = mid;
        }
        n0 = lo;
    }
    int cur_node = n0 + ((wv - (n0 & 7)) & 7);
    float a[8];
    #pragma unroll
    for (int q = 0; q < 8; ++q) a[q] = 0.0f;
    float den = 0.0f;

    float ts_cur, ts_nxt;
    int sv_nxt[2];
    {
        int sv0[2];
        load_meta(mt, t0, E, rbase, g, trow, sv0, ts_cur);
        #pragma unroll
        for (int i = 0; i < 2; ++i) {
            const int rlo = (rbase + i * 4 + g) & 15;
            const unsigned short* gsrc = xb + (size_t)sv0[i] * IN_CHN + ((c16 ^ rlo) * 8);
            GLL16(gsrc, &xs[0][rbase + i * 4][0]);
        }
        int t1 = t0 + 1;
        load_meta(mt, t1 < tend ? t1 : tend - 1, E, rbase, g, trow, sv_nxt, ts_nxt);
    }

    int cur = 0;
    for (int tile = t0; tile < tend; ++tile) {
        const int e0 = tile * TM;
        const int e1 = e0 + TM;

        // ---- compute te(t) pack in registers (overlaps gll(t) drain) ----
        ushort4 tp[2];
        {
            float v[8];
            #pragma unroll
            for (int j = 0; j < 8; ++j)
                v[j] = __sinf(ts_cur * frv[j] + coff);
            tp[0] = (ushort4){ f2b(v[0]), f2b(v[1]), f2b(v[2]), f2b(v[3]) };
            tp[1] = (ushort4){ f2b(v[4]), f2b(v[5]), f2b(v[6]), f2b(v[7]) };
        }
        // ---- prefetch meta(t+2) ----
        int sv2[2]; float ts2;
        {
            int t2 = tile + 2;
            load_meta(mt, t2 < tend ? t2 : tend - 1, E, rbase, g, trow, sv2, ts2);
        }

        __syncthreads();   // A: drains gll(t); agg(t-1) LDS reads complete

        // ---- issue gll(t+1) -> xs[cur^1] ----
        if (tile + 1 < tend) {
            #pragma unroll
            for (int i = 0; i < 2; ++i) {
                const int rlo = (rbase + i * 4 + g) & 15;
                const unsigned short* gsrc = xb + (size_t)sv_nxt[i] * IN_CHN + ((c16 ^ rlo) * 8);
                GLL16(gsrc, &xs[cur ^ 1][rbase + i * 4][0]);
            }
        }
        // ---- write te(t) (granule-swizzled) + zero exs (exs above te's 8K) ----
        {
            unsigned short* tr = &te[trow * 64];
            int slot = (tpart ^ (trow & 7)) * 8;
            *(ushort4*)(tr + slot)     = tp[0];
            *(ushort4*)(tr + slot + 4) = tp[1];
            if (tid < TM) exs[tid] = 0.0f;
        }

        LDS_BARRIER();     // B: te + exs-zero visible; gll(t+1) in flight

        // ---- MFMA ----
        f32x4 acc[4];
        #pragma unroll
        for (int mi = 0; mi < 4; ++mi) acc[mi] = (f32x4){0.f, 0.f, 0.f, 0.f};

        __builtin_amdgcn_s_setprio(1);
        const unsigned short* xsc = &xs[cur][0][0];
        #pragma unroll
        for (int mi = 0; mi < 4; ++mi) {
            const int r = mi * 16 + c16;
            const unsigned short* xrow = xsc + r * 128;
            #pragma unroll
            for (int kk = 0; kk < 4; ++kk) {
                const int slot = ((kk << 2) + g) ^ c16;   // source-swizzled granule
                bf16x8 av = __builtin_bit_cast(bf16x8, *(const uint4*)(xrow + slot * 8));
                acc[mi] = __builtin_amdgcn_mfma_f32_16x16x32_bf16(Wf[kk], av, acc[mi], 0, 0, 0);
            }
            const unsigned short* trw = &te[r * 64];
            bf16x8 s8 = __builtin_bit_cast(bf16x8, *(const uint4*)(trw + ((g ^ (r & 7)) * 8)));
            bf16x8 c8 = __builtin_bit_cast(bf16x8, *(const uint4*)(trw + (((g + 4) ^ (r & 7)) * 8)));
            acc[mi] = __builtin_amdgcn_mfma_f32_16x16x32_bf16(Wf[4], s8, acc[mi], 0, 0, 0);
            acc[mi] = __builtin_amdgcn_mfma_f32_16x16x32_bf16(Wf[5], c8, acc[mi], 0, 0, 0);
        }
        __builtin_amdgcn_s_setprio(0);

        LDS_BARRIER();     // C: all te reads done -> hx (union) writable

        // ---- epilogue: tanh, h -> hx LDS, alpha -> exs (LDS atomic) ----
        #pragma unroll
        for (int mi = 0; mi < 4; ++mi) {
            const int r = mi * 16 + c16;
            f32x4 z = acc[mi];
            float p = 0.0f;
            #pragma unroll
            for (int q = 0; q < 4; ++q) {
                float h = fast_tanh(z[q] + bias_v[q]);
                z[q] = h;
                p = fmaf(h, attn_v[q], p);
            }
            ushort4 pv = (ushort4){ f2b(z[0]), f2b(z[1]), f2b(z[2]), f2b(z[3]) };
            *(ushort4*)&hx[r * HXP + wbase + g * 4] = pv;
            p += __shfl_xor(p, 16);
            p += __shfl_xor(p, 32);
            if (g == 0) atomicAdd(&exs[r], p);
        }

        LDS_BARRIER();     // D: hx + exs complete; gll(t+1) still in flight

        // ---- aggregation: wave w walks its nodes in [e0, e1) ----
        while (cur_node < Nn) {
            int s  = offs[cur_node];
            if (s >= e1) break;
            int en = offs[cur_node + 1];
            int lo = s > e0 ? s : e0;
            int hi = en < e1 ? en : e1;
            for (int i = lo + sub; i < hi; i += 4) {
                int li = i - e0;
                float ex = __expf(exs[li]);
                uint4 hv = *(const uint4*)&hx[li * HXP + chl * 8];
                den += ex;
                unsigned int hw[4] = { hv.x, hv.y, hv.z, hv.w };
                #pragma unroll
                for (int q = 0; q < 4; ++q) {
                    a[2*q]   = fmaf(ex, b2f((unsigned short)(hw[q] & 0xFFFFu)), a[2*q]);
                    a[2*q+1] = fmaf(ex, b2f((unsigned short)(hw[q] >> 16)),     a[2*q+1]);
                }
            }
            if (en <= e1) {
                // node complete: reduce across subs; ALWAYS plain store
                #pragma unroll
                for (int q = 0; q < 8; ++q) {
                    a[q] += __shfl_xor(a[q], 16);
                    a[q] += __shfl_xor(a[q], 32);
                }
                float ds = den + __shfl_xor(den, 16);
                ds += __shfl_xor(ds, 32);
                if (sub == 0) {
                    float* op = out + (size_t)cur_node * OUT_CHN + chl * 8;
                    *(float4*)op       = (float4){a[0], a[1], a[2], a[3]};
                    *(float4*)(op + 4) = (float4){a[4], a[5], a[6], a[7]};
                    if (chl == 0) den_g[cur_node] = ds;
                }
                #pragma unroll
                for (int q = 0; q < 8; ++q) a[q] = 0.0f;
                den = 0.0f;
                cur_node += 8;
            } else break;   // carries into next tile
        }

        ts_cur = ts_nxt; ts_nxt = ts2;
        sv_nxt[0] = sv2[0]; sv_nxt[1] = sv2[1];
        cur ^= 1;
    }

    // ---- block-end flush: carried straddler -> side buffer (no atomics) ----
    if (cur_node < Nn) {
        int s = offs[cur_node];
        if (s < bend && offs[cur_node + 1] > bend) {
            #pragma unroll
            for (int q = 0; q < 8; ++q) {
                a[q] += __shfl_xor(a[q], 16);
                a[q] += __shfl_xor(a[q], 32);
            }
            float ds = den + __shfl_xor(den, 16);
            ds += __shfl_xor(ds, 32);
            if (sub == 0) {
                float* sv = side_val + (size_t)b * OUT_CHN + chl * 8;
                *(float4*)sv       = (float4){a[0], a[1], a[2], a[3]};
                *(float4*)(sv + 4) = (float4){a[4], a[5], a[6], a[7]};
                if (chl == 0) {
                    side_den[b] = ds;
                    side_node[b] = cur_node;
                }
            }
        }
    }
}

// ---------------- fixup: add side partials into out/den (after gemm) ----------------

__global__ __launch_bounds__(256) void fixup(const int* __restrict__ side_node,
    const float* __restrict__ side_den, const float* __restrict__ side_val,
    float* __restrict__ out, float* __restrict__ den_g, int nb)
{
    int w = (blockIdx.x * 256 + threadIdx.x) >> 6;
    int lane = threadIdx.x & 63;
    if (w >= nb) return;
    int node = side_node[w];
    if (node < 0) return;
    const float* sv = side_val + (size_t)w * OUT_CHN;
    float* op = out + (size_t)node * OUT_CHN;
    atomicAdd(op + lane * 2,     sv[lane * 2]);
    atomicAdd(op + lane * 2 + 1, sv[lane * 2 + 1]);
    if (lane == 0) atomicAdd(&den_g[node], side_den[w]);
}

// ---------------- normalize: out = out_raw / den; deg-0 nodes -> 0 ----------------

__global__ __launch_bounds__(256) void normalize(float* __restrict__ out,
    const float* __restrict__ den_g, const int* __restrict__ offs, int Nn)
{
    int gid = blockIdx.x * 256 + threadIdx.x;   // one float4 per thread
    int n = gid >> 5;
    if (n >= Nn) return;
    int c = (gid & 31) * 4;
    float4* p = (float4*)(out + (size_t)n * OUT_CHN + c);
    if (offs[n + 1] == offs[n]) { *p = (float4){0, 0, 0, 0}; return; }
    float rs = __builtin_amdgcn_rcpf(den_g[n] + 1e-16f);
    float4 v = *p;
    v.x *= rs; v.y *= rs; v.z *= rs; v.w *= rs;
    *p = v;
}

// ---------------- launch ----------------

extern "C" void kernel_launch(void* const* d_in, const int* in_sizes, int n_in,
                              void* d_out, int out_size, void* d_ws, size_t ws_size,
                              hipStream_t stream) {
    const float* x     = (const float*)d_in[0];
    const int*   ei    = (const int*)d_in[1];     // [2, E]
    const float* et    = (const float*)d_in[2];
    const float* freqs = (const float*)d_in[3];
    const float* lw    = (const float*)d_in[4];   // [128, 192]
    const float* lb    = (const float*)d_in[5];
    const float* attn  = (const float*)d_in[6];
    float* out = (float*)d_out;

    const int E  = in_sizes[2];
    const int Nn = in_sizes[0] / IN_CHN;
    const int NB = 768;                            // 3 blocks/CU exactly

    // workspace layout
    char* ws = (char*)d_ws;
    uint2* mt      = (uint2*)ws;         size_t off = (size_t)E * sizeof(uint2);
    unsigned short* xb = (unsigned short*)(ws + off); off += (size_t)Nn * IN_CHN * sizeof(unsigned short);
    float* den_g   = (float*)(ws + off); off += (size_t)Nn * sizeof(float);
    int*   deg     = (int*)(ws + off);   off += (size_t)Nn * sizeof(int);
    int*   offs    = (int*)(ws + off);   off += (size_t)(Nn + 1) * sizeof(int);
    int*   cursor  = (int*)(ws + off);   off += (size_t)Nn * sizeof(int);
    int*   partial = (int*)(ws + off);   off += 1024 * sizeof(int);
    int*   side_node = (int*)(ws + off); off += (size_t)NB * sizeof(int);
    float* side_den  = (float*)(ws + off); off += (size_t)NB * sizeof(float);
    float* side_val  = (float*)(ws + off);

    const int nblk = (Nn + 255) / 256;
    const int eblk = (E + 255) / 256;

    long long n8 = (long long)Nn * IN_CHN / 8;
    cvt_init<<<(unsigned)((n8 + 255) / 256), 256, 0, stream>>>(x, xb, deg, side_node, n8, Nn, NB);

    count_deg<<<eblk, 256, 0, stream>>>(ei, deg, E);
    scan_local<<<nblk, 256, 0, stream>>>(deg, offs, partial, Nn);
    finalize2<<<nblk, 256, 0, stream>>>(offs, partial, cursor, Nn, E, nblk);
    fill_perm<<<eblk, 256, 0, stream>>>(ei, et, cursor, mt, E);

    const int n_tiles = (E + TM - 1) / TM;
    const int kq = n_tiles / NB, kr = n_tiles % NB;
    gemm_fused<<<NB, 512, 0, stream>>>(xb, mt, offs, freqs, lw, lb, attn,
                                       out, den_g, side_node, side_den, side_val,
                                       E, Nn, n_tiles, kq, kr);

    fixup<<<(NB * 64 + 255) / 256, 256, 0, stream>>>(side_node, side_den, side_val,
                                                     out, den_g, NB);

    normalize<<<(Nn * 32 + 255) / 256, 256, 0, stream>>>(out, den_g, offs, Nn);
}

// Round 12
// 234.701 us; speedup vs baseline: 1.1049x; 1.0669x over previous
//
#include <hip/hip_runtime.h>
#include <hip/hip_bf16.h>
#include <math.h>

#define IN_CHN 128
#define OUT_CHN 128
#define KD 192
#define TM 64                  // edges per tile
#define HXP 136                // hx row stride in ushorts (272B, 16B-aligned)

typedef __bf16 bf16x8 __attribute__((ext_vector_type(8)));
typedef float f32x4 __attribute__((ext_vector_type(4)));

static __device__ __forceinline__ unsigned short f2b(float f) {
    return __builtin_bit_cast(unsigned short, (__bf16)f);   // RNE
}
static __device__ __forceinline__ float b2f(unsigned short b) {
    return __uint_as_float(((unsigned int)b) << 16);
}
static __device__ __forceinline__ float fast_tanh(float x) {
    float e = __expf(2.0f * x);
    return 1.0f - 2.0f * __builtin_amdgcn_rcpf(e + 1.0f);
}

// async global->LDS, 16B per lane; LDS dest wave-uniform base + lane*16
#define GLL16(gsrc, ldst) \
    __builtin_amdgcn_global_load_lds( \
        (const __attribute__((address_space(1))) unsigned int*)(gsrc), \
        (__attribute__((address_space(3))) unsigned int*)(ldst), 16, 0, 0)

// light barrier: cross-wave LDS visibility WITHOUT draining vmcnt (keeps
// in-flight global_load_lds alive across it)
#define LDS_BARRIER() do { \
    asm volatile("s_waitcnt lgkmcnt(0)" ::: "memory"); \
    __builtin_amdgcn_s_barrier(); \
    __builtin_amdgcn_sched_barrier(0); \
} while (0)

// ---------------- x -> bf16 + init deg/side ----------------

__global__ __launch_bounds__(256) void cvt_init(const float* __restrict__ x,
    unsigned short* __restrict__ xb, int* __restrict__ deg,
    int* __restrict__ side_node, long long n8, int Nn, int nb)
{
    long long i = (long long)blockIdx.x * 256 + threadIdx.x;
    if (i < n8) {
        const float4* src = (const float4*)(x + i * 8);
        float4 v0 = src[0], v1 = src[1];
        ushort4 p0 = { f2b(v0.x), f2b(v0.y), f2b(v0.z), f2b(v0.w) };
        ushort4 p1 = { f2b(v1.x), f2b(v1.y), f2b(v1.z), f2b(v1.w) };
        *(ushort4*)(xb + i * 8)     = p0;
        *(ushort4*)(xb + i * 8 + 4) = p1;
    }
    int t = (int)i;
    if (t < Nn) deg[t] = 0;
    if (t < nb) side_node[t] = -1;
}

// ---------------- CSR build ----------------

__global__ __launch_bounds__(256) void count_deg(const int* __restrict__ ei,
                                                 int* __restrict__ deg, int E) {
    int e = blockIdx.x * 256 + threadIdx.x;
    if (e < E) atomicAdd(&deg[ei[E + e]], 1);
}

static __device__ __forceinline__ int wave_incl_scan(int v, int lane) {
    #pragma unroll
    for (int off = 1; off < 64; off <<= 1) {
        int t = __shfl_up(v, off);
        if (lane >= off) v += t;
    }
    return v;
}

__global__ __launch_bounds__(256) void scan_local(const int* __restrict__ deg,
    int* __restrict__ offs, int* __restrict__ partial, int Nn)
{
    __shared__ int wsum[4];
    int tid = threadIdx.x, lane = tid & 63, wid = tid >> 6;
    int i = blockIdx.x * 256 + tid;
    int v = (i < Nn) ? deg[i] : 0;
    int incl = wave_incl_scan(v, lane);
    if (lane == 63) wsum[wid] = incl;
    __syncthreads();
    int wpre = 0;
    for (int w = 0; w < wid; ++w) wpre += wsum[w];
    if (i < Nn) offs[i] = wpre + incl - v;
    if (tid == 255) partial[blockIdx.x] = wpre + incl;
}

// per-block: sum partials[0..b) directly (nblk <= 256), add, write cursor
__global__ __launch_bounds__(256) void finalize2(int* __restrict__ offs,
    const int* __restrict__ partial, int* __restrict__ cursor,
    int Nn, int E, int nblk)
{
    __shared__ int wsum[4];
    int b = blockIdx.x, tid = threadIdx.x, lane = tid & 63, wid = tid >> 6;
    int v = (tid < b && tid < nblk) ? partial[tid] : 0;
    #pragma unroll
    for (int off = 32; off > 0; off >>= 1) v += __shfl_xor(v, off);
    if (lane == 0) wsum[wid] = v;
    __syncthreads();
    int bp = wsum[0] + wsum[1] + wsum[2] + wsum[3];
    int i = b * 256 + tid;
    if (i < Nn) {
        int o = offs[i] + bp;
        offs[i] = o; cursor[i] = o;
        if (i == Nn - 1) offs[Nn] = E;   // sentinel
    }
}

// scatter (src, t) into CSR-permuted order as one 8B store
__global__ __launch_bounds__(256) void fill_perm(const int* __restrict__ ei,
    const float* __restrict__ et, int* __restrict__ cursor,
    uint2* __restrict__ mt, int E)
{
    int e = blockIdx.x * 256 + threadIdx.x;
    if (e < E) {
        int d = ei[E + e];
        int pos = atomicAdd(&cursor[d], 1);
        mt[pos] = make_uint2((unsigned)ei[e], __float_as_uint(et[e]));
    }
}

// ---------------- fused MFMA GEMM + softmax aggregation ----------------
// Per edge (CSR order): h = tanh([x[src], te(t)] @ W^T + b), ex = exp(h.attn).
// out_raw[dst] += ex*h, den[dst] += ex accumulate in-kernel (hx tile in LDS,
// exs via LDS atomics). Blocks own contiguous tile ranges; wave w aggregates
// nodes n%8==w with register carry. Completed node -> PLAIN store; block-end
// straddler -> side[] combined by fixup().
// TWO barriers per tile: te/exs double-buffered so te(t+1) is written BEFORE
// A while agg(t) runs. Hazards: te(t+1)-write vs MFMA(t-1) te-read -> C(t-1);
// hx(t)/exs-zero writes vs agg(t-1) reads -> A(t); gll(t+1) vs MFMA(t-1)
// xs-reads -> C(t-1)+A(t); MFMA(t) needs gll(t) -> vmcnt drain at A(t).
// LDS = 32K xs + 16K te-dbuf + 17K hx + 0.5K exs = 67072 B -> 2 blocks/CU.

__device__ __forceinline__ void load_meta(const uint2* __restrict__ mt,
    int tile, int E, int rbase, int g, int trow, int sv[2], float& tsv)
{
    int e0 = tile * TM;
    #pragma unroll
    for (int i = 0; i < 2; ++i) {
        int e = e0 + rbase + i * 4 + g;
        sv[i] = (int)mt[e < E ? e : E - 1].x;
    }
    int el = e0 + trow;
    tsv = __uint_as_float(mt[el < E ? el : E - 1].y);
}

__global__ __launch_bounds__(512) void gemm_fused(
    const unsigned short* __restrict__ xb, const uint2* __restrict__ mt,
    const int* __restrict__ offs,
    const float* __restrict__ freqs, const float* __restrict__ lw,
    const float* __restrict__ lb, const float* __restrict__ attn,
    float* __restrict__ out, float* __restrict__ den_g,
    int* __restrict__ side_node, float* __restrict__ side_den,
    float* __restrict__ side_val,
    int E, int Nn, int n_tiles, int kq, int kr)
{
    __shared__ unsigned short xs[2][TM][128];   // 32768 B x tile (dbuf)
    __shared__ unsigned short te[2][TM * 64];   // 16384 B te tile (dbuf, swizzled)
    __shared__ unsigned short hx[TM * HXP];     // 17408 B h tile
    __shared__ float exs[2][TM];                //   512 B alpha accumulators (dbuf)

    const int b    = blockIdx.x;
    const int t0   = b * kq + min(b, kr);
    const int cnt  = kq + (b < kr ? 1 : 0);
    if (cnt <= 0 || t0 >= n_tiles) return;
    const int tend = min(t0 + cnt, n_tiles);
    const int be0  = t0 * TM;
    const int bend = min(tend * TM, E);

    const int tid  = threadIdx.x;
    const int lane = tid & 63;
    const int wv   = tid >> 6;          // wave 0..7
    const int c16  = lane & 15;
    const int g    = lane >> 4;         // 0..3
    const int wbase = wv * 16;          // this wave's channel base
    const int rbase = wv * 8;           // this wave's gll row base
    const int trow  = tid >> 3;         // te row 0..63
    const int tpart = tid & 7;          // te part (0-3 sin, 4-7 cos)
    const int sub  = lane >> 4;         // agg: edge subgroup 0..3
    const int chl  = lane & 15;         // agg: channel lane (8 ch)

    // W frags in registers: lane's row(ch) = wbase+c16; k = kk*32+g*8+j
    bf16x8 Wf[6];
    #pragma unroll
    for (int kk = 0; kk < 6; ++kk) {
        const float* wp = lw + (size_t)(wbase + c16) * KD + kk * 32 + g * 8;
        float4 v0 = *(const float4*)wp;
        float4 v1 = *(const float4*)(wp + 4);
        bf16x8 bb;
        bb[0] = (__bf16)v0.x; bb[1] = (__bf16)v0.y; bb[2] = (__bf16)v0.z; bb[3] = (__bf16)v0.w;
        bb[4] = (__bf16)v1.x; bb[5] = (__bf16)v1.y; bb[6] = (__bf16)v1.z; bb[7] = (__bf16)v1.w;
        Wf[kk] = bb;
    }
    const f32x4 bias_v = *(const f32x4*)(lb   + wbase + g * 4);
    const f32x4 attn_v = *(const f32x4*)(attn + wbase + g * 4);

    const float coff = (tpart >= 4) ? 1.5707963267948966f : 0.0f;  // cos = sin(x+pi/2)
    float frv[8];
    #pragma unroll
    for (int j = 0; j < 8; ++j) frv[j] = freqs[(tpart & 3) * 8 + j] * 6.283185307179586f;

    // ---- first node of block: binary search offs (uniform across threads) ----
    int n0;
    {
        int lo = 0, hi = Nn;
        while (lo + 1 < hi) {
            int mid = (lo + hi) >> 1;
            if (offs[mid] <= be0) lo = mid; else hi = mid;
        }
        n0 = lo;
    }
    int cur_node = n0 + ((wv - (n0 & 7)) & 7);
    float a[8];
    #pragma unroll
    for (int q = 0; q < 8; ++q) a[q] = 0.0f;
    float den = 0.0f;

    // ---- prologue: meta(t0), gll(t0)->xs[0], te(t0)->te[0], exs[0]=0, meta(t1) ----
    float ts_nxt;
    int sv_nxt[2];
    {
        int sv0[2]; float ts0;
        load_meta(mt, t0, E, rbase, g, trow, sv0, ts0);
        #pragma unroll
        for (int i = 0; i < 2; ++i) {
            const int rlo = (rbase + i * 4 + g) & 15;
            const unsigned short* gsrc = xb + (size_t)sv0[i] * IN_CHN + ((c16 ^ rlo) * 8);
            GLL16(gsrc, &xs[0][rbase + i * 4][0]);
        }
        // te(t0) -> te[0]
        float v[8];
        #pragma unroll
        for (int j = 0; j < 8; ++j)
            v[j] = __sinf(ts0 * frv[j] + coff);
        unsigned short* tr = &te[0][trow * 64];
        int slot = (tpart ^ (trow & 7)) * 8;
        *(ushort4*)(tr + slot)     = (ushort4){ f2b(v[0]), f2b(v[1]), f2b(v[2]), f2b(v[3]) };
        *(ushort4*)(tr + slot + 4) = (ushort4){ f2b(v[4]), f2b(v[5]), f2b(v[6]), f2b(v[7]) };
        if (tid < TM) exs[0][tid] = 0.0f;

        int t1 = t0 + 1;
        load_meta(mt, t1 < tend ? t1 : tend - 1, E, rbase, g, trow, sv_nxt, ts_nxt);
    }

    int cur = 0;
    for (int tile = t0; tile < tend; ++tile) {
        const int e0 = tile * TM;
        const int e1 = e0 + TM;

        // ---- compute + write te(t+1) -> te[cur^1] (pre-A; safe via C(t-1)) ----
        {
            float v[8];
            #pragma unroll
            for (int j = 0; j < 8; ++j)
                v[j] = __sinf(ts_nxt * frv[j] + coff);
            unsigned short* tr = &te[cur ^ 1][trow * 64];
            int slot = (tpart ^ (trow & 7)) * 8;
            *(ushort4*)(tr + slot)     = (ushort4){ f2b(v[0]), f2b(v[1]), f2b(v[2]), f2b(v[3]) };
            *(ushort4*)(tr + slot + 4) = (ushort4){ f2b(v[4]), f2b(v[5]), f2b(v[6]), f2b(v[7]) };
        }
        // ---- prefetch meta(t+2) ----
        int sv2[2]; float ts2;
        {
            int t2 = tile + 2;
            load_meta(mt, t2 < tend ? t2 : tend - 1, E, rbase, g, trow, sv2, ts2);
        }

        __syncthreads();   // A: drains gll(t); publishes te(t), exs(t)=0;
                           //    agg(t-1) hx/exs reads complete

        // ---- issue gll(t+1) -> xs[cur^1]; zero exs(t+1) ----
        if (tile + 1 < tend) {
            #pragma unroll
            for (int i = 0; i < 2; ++i) {
                const int rlo = (rbase + i * 4 + g) & 15;
                const unsigned short* gsrc = xb + (size_t)sv_nxt[i] * IN_CHN + ((c16 ^ rlo) * 8);
                GLL16(gsrc, &xs[cur ^ 1][rbase + i * 4][0]);
            }
        }
        if (tid < TM) exs[cur ^ 1][tid] = 0.0f;

        // ---- MFMA: x frags from swizzled LDS, te frags from LDS ----
        f32x4 acc[4];
        #pragma unroll
        for (int mi = 0; mi < 4; ++mi) acc[mi] = (f32x4){0.f, 0.f, 0.f, 0.f};

        __builtin_amdgcn_s_setprio(1);
        const unsigned short* xsc = &xs[cur][0][0];
        const unsigned short* tec = &te[cur][0];
        #pragma unroll
        for (int mi = 0; mi < 4; ++mi) {
            const int r = mi * 16 + c16;
            const unsigned short* xrow = xsc + r * 128;
            #pragma unroll
            for (int kk = 0; kk < 4; ++kk) {
                const int slot = ((kk << 2) + g) ^ c16;   // source-swizzled granule
                bf16x8 av = __builtin_bit_cast(bf16x8, *(const uint4*)(xrow + slot * 8));
                acc[mi] = __builtin_amdgcn_mfma_f32_16x16x32_bf16(Wf[kk], av, acc[mi], 0, 0, 0);
            }
            const unsigned short* trw = tec + r * 64;
            bf16x8 s8 = __builtin_bit_cast(bf16x8, *(const uint4*)(trw + ((g ^ (r & 7)) * 8)));
            bf16x8 c8 = __builtin_bit_cast(bf16x8, *(const uint4*)(trw + (((g + 4) ^ (r & 7)) * 8)));
            acc[mi] = __builtin_amdgcn_mfma_f32_16x16x32_bf16(Wf[4], s8, acc[mi], 0, 0, 0);
            acc[mi] = __builtin_amdgcn_mfma_f32_16x16x32_bf16(Wf[5], c8, acc[mi], 0, 0, 0);
        }
        __builtin_amdgcn_s_setprio(0);

        // ---- epilogue: tanh, h -> hx LDS, alpha -> exs[cur] (LDS atomic) ----
        #pragma unroll
        for (int mi = 0; mi < 4; ++mi) {
            const int r = mi * 16 + c16;
            f32x4 z = acc[mi];
            float p = 0.0f;
            #pragma unroll
            for (int q = 0; q < 4; ++q) {
                float h = fast_tanh(z[q] + bias_v[q]);
                z[q] = h;
                p = fmaf(h, attn_v[q], p);
            }
            ushort4 pv = (ushort4){ f2b(z[0]), f2b(z[1]), f2b(z[2]), f2b(z[3]) };
            *(ushort4*)&hx[r * HXP + wbase + g * 4] = pv;
            p += __shfl_xor(p, 16);
            p += __shfl_xor(p, 32);
            if (g == 0) atomicAdd(&exs[cur][r], p);
        }

        LDS_BARRIER();     // C: hx + exs(t) complete; gll(t+1) still in flight

        // ---- aggregation: wave w walks its nodes in [e0, e1) ----
        while (cur_node < Nn) {
            int s  = offs[cur_node];
            if (s >= e1) break;
            int en = offs[cur_node + 1];
            int lo = s > e0 ? s : e0;
            int hi = en < e1 ? en : e1;
            for (int i = lo + sub; i < hi; i += 4) {
                int li = i - e0;
                float ex = __expf(exs[cur][li]);
                uint4 hv = *(const uint4*)&hx[li * HXP + chl * 8];
                den += ex;
                unsigned int hw[4] = { hv.x, hv.y, hv.z, hv.w };
                #pragma unroll
                for (int q = 0; q < 4; ++q) {
                    a[2*q]   = fmaf(ex, b2f((unsigned short)(hw[q] & 0xFFFFu)), a[2*q]);
                    a[2*q+1] = fmaf(ex, b2f((unsigned short)(hw[q] >> 16)),     a[2*q+1]);
                }
            }
            if (en <= e1) {
                // node complete: reduce across subs; ALWAYS plain store
                #pragma unroll
                for (int q = 0; q < 8; ++q) {
                    a[q] += __shfl_xor(a[q], 16);
                    a[q] += __shfl_xor(a[q], 32);
                }
                float ds = den + __shfl_xor(den, 16);
                ds += __shfl_xor(ds, 32);
                if (sub == 0) {
                    float* op = out + (size_t)cur_node * OUT_CHN + chl * 8;
                    *(float4*)op       = (float4){a[0], a[1], a[2], a[3]};
                    *(float4*)(op + 4) = (float4){a[4], a[5], a[6], a[7]};
                    if (chl == 0) den_g[cur_node] = ds;
                }
                #pragma unroll
                for (int q = 0; q < 8; ++q) a[q] = 0.0f;
                den = 0.0f;
                cur_node += 8;
            } else break;   // carries into next tile
        }

        ts_nxt = ts2;
        sv_nxt[0] = sv2[0]; sv_nxt[1] = sv2[1];
        cur ^= 1;
    }

    // ---- block-end flush: carried straddler -> side buffer (no atomics) ----
    if (cur_node < Nn) {
        int s = offs[cur_node];
        if (s < bend && offs[cur_node + 1] > bend) {
            #pragma unroll
            for (int q = 0; q < 8; ++q) {
                a[q] += __shfl_xor(a[q], 16);
                a[q] += __shfl_xor(a[q], 32);
            }
            float ds = den + __shfl_xor(den, 16);
            ds += __shfl_xor(ds, 32);
            if (sub == 0) {
                float* sv = side_val + (size_t)b * OUT_CHN + chl * 8;
                *(float4*)sv       = (float4){a[0], a[1], a[2], a[3]};
                *(float4*)(sv + 4) = (float4){a[4], a[5], a[6], a[7]};
                if (chl == 0) {
                    side_den[b] = ds;
                    side_node[b] = cur_node;
                }
            }
        }
    }
}

// ---------------- fixup: add side partials into out/den (after gemm) ----------------

__global__ __launch_bounds__(256) void fixup(const int* __restrict__ side_node,
    const float* __restrict__ side_den, const float* __restrict__ side_val,
    float* __restrict__ out, float* __restrict__ den_g, int nb)
{
    int w = (blockIdx.x * 256 + threadIdx.x) >> 6;
    int lane = threadIdx.x & 63;
    if (w >= nb) return;
    int node = side_node[w];
    if (node < 0) return;
    const float* sv = side_val + (size_t)w * OUT_CHN;
    float* op = out + (size_t)node * OUT_CHN;
    atomicAdd(op + lane * 2,     sv[lane * 2]);
    atomicAdd(op + lane * 2 + 1, sv[lane * 2 + 1]);
    if (lane == 0) atomicAdd(&den_g[node], side_den[w]);
}

// ---------------- normalize: out = out_raw / den; deg-0 nodes -> 0 ----------------

__global__ __launch_bounds__(256) void normalize(float* __restrict__ out,
    const float* __restrict__ den_g, const int* __restrict__ offs, int Nn)
{
    int gid = blockIdx.x * 256 + threadIdx.x;   // one float4 per thread
    int n = gid >> 5;
    if (n >= Nn) return;
    int c = (gid & 31) * 4;
    float4* p = (float4*)(out + (size_t)n * OUT_CHN + c);
    if (offs[n + 1] == offs[n]) { *p = (float4){0, 0, 0, 0}; return; }
    float rs = __builtin_amdgcn_rcpf(den_g[n] + 1e-16f);
    float4 v = *p;
    v.x *= rs; v.y *= rs; v.z *= rs; v.w *= rs;
    *p = v;
}

// ---------------- launch ----------------

extern "C" void kernel_launch(void* const* d_in, const int* in_sizes, int n_in,
                              void* d_out, int out_size, void* d_ws, size_t ws_size,
                              hipStream_t stream) {
    const float* x     = (const float*)d_in[0];
    const int*   ei    = (const int*)d_in[1];     // [2, E]
    const float* et    = (const float*)d_in[2];
    const float* freqs = (const float*)d_in[3];
    const float* lw    = (const float*)d_in[4];   // [128, 192]
    const float* lb    = (const float*)d_in[5];
    const float* attn  = (const float*)d_in[6];
    float* out = (float*)d_out;

    const int E  = in_sizes[2];
    const int Nn = in_sizes[0] / IN_CHN;
    const int NB = 512;                            // 2 blocks/CU (LDS-capped)

    // workspace layout
    char* ws = (char*)d_ws;
    uint2* mt      = (uint2*)ws;         size_t off = (size_t)E * sizeof(uint2);
    unsigned short* xb = (unsigned short*)(ws + off); off += (size_t)Nn * IN_CHN * sizeof(unsigned short);
    float* den_g   = (float*)(ws + off); off += (size_t)Nn * sizeof(float);
    int*   deg     = (int*)(ws + off);   off += (size_t)Nn * sizeof(int);
    int*   offs    = (int*)(ws + off);   off += (size_t)(Nn + 1) * sizeof(int);
    int*   cursor  = (int*)(ws + off);   off += (size_t)Nn * sizeof(int);
    int*   partial = (int*)(ws + off);   off += 1024 * sizeof(int);
    int*   side_node = (int*)(ws + off); off += (size_t)NB * sizeof(int);
    float* side_den  = (float*)(ws + off); off += (size_t)NB * sizeof(float);
    float* side_val  = (float*)(ws + off);

    const int nblk = (Nn + 255) / 256;
    const int eblk = (E + 255) / 256;

    long long n8 = (long long)Nn * IN_CHN / 8;
    cvt_init<<<(unsigned)((n8 + 255) / 256), 256, 0, stream>>>(x, xb, deg, side_node, n8, Nn, NB);

    count_deg<<<eblk, 256, 0, stream>>>(ei, deg, E);
    scan_local<<<nblk, 256, 0, stream>>>(deg, offs, partial, Nn);
    finalize2<<<nblk, 256, 0, stream>>>(offs, partial, cursor, Nn, E, nblk);
    fill_perm<<<eblk, 256, 0, stream>>>(ei, et, cursor, mt, E);

    const int n_tiles = (E + TM - 1) / TM;
    const int kq = n_tiles / NB, kr = n_tiles % NB;
    gemm_fused<<<NB, 512, 0, stream>>>(xb, mt, offs, freqs, lw, lb, attn,
                                       out, den_g, side_node, side_den, side_val,
                                       E, Nn, n_tiles, kq, kr);

    fixup<<<(NB * 64 + 255) / 256, 256, 0, stream>>>(side_node, side_den, side_val,
                                                     out, den_g, NB);

    normalize<<<(Nn * 32 + 255) / 256, 256, 0, stream>>>(out, den_g, offs, Nn);
}